// Round 1
// baseline (288.269 us; speedup 1.0000x reference)
//
#include <hip/hip_runtime.h>
#include <math.h>

#define BATCH   64
#define MAXLEN  512
#define EMB     128
#define REGION  7
#define RADIUS  3
#define ENTIRE  506          // MAXLEN - 2*RADIUS
#define NCLS    20
#define AGG1    1024         // MAXLEN*2
#define TILE_N  16
#define ICP     512          // interC padded row stride (16B-aligned rows)

// ---------------------------------------------------------------------------
// Kernel 1: per (b, 16-position tile):
//   inter[n][e] = relu(max_j emb_word[w(n+j)][e] * emb_region[w(n+3)][j*128+e])
//   interC[b][c][n] = sum_e inter[n][e] * W_inter[c][e]
// Word-embedding rows staged in LDS (22 rows per tile -> 7x gather reuse).
// ---------------------------------------------------------------------------
__global__ __launch_bounds__(256) void k1_inter(
        const int*   __restrict__ ti,
        const float* __restrict__ embR,
        const float* __restrict__ embW,
        const float* __restrict__ Wint,
        float*       __restrict__ interC) {
    __shared__ float wordbuf[TILE_N + 6][EMB];     // no pad: reads are e-consecutive
    __shared__ float interL[TILE_N][EMB + 1];      // pad -> phase2 reads conflict-free
    __shared__ float wl[NCLS][EMB + 2];            // pad -> phase2 reads conflict-free
    __shared__ int   wid[TILE_N + 6];

    const int b   = blockIdx.y;
    const int n0  = blockIdx.x * TILE_N;
    const int np  = min(TILE_N, ENTIRE - n0);
    const int tid = threadIdx.x;

    // phase A: word ids + W_inter into LDS
    if (tid < TILE_N + 6) {
        int r = tid;
        wid[r] = (n0 + r < MAXLEN) ? ti[b * MAXLEN + n0 + r] : 0;
    }
    for (int idx = tid; idx < NCLS * EMB; idx += 256) {
        int c = idx >> 7, e = idx & 127;
        wl[c][e] = Wint[idx];
    }
    __syncthreads();

    // phase B: gather word-embedding rows (coalesced per row)
    for (int idx = tid; idx < (TILE_N + 6) * EMB; idx += 256) {
        int r = idx >> 7, e = idx & 127;
        wordbuf[r][e] = embW[(long)wid[r] * EMB + e];
    }
    __syncthreads();

    // phase C: region max + relu. 2 positions per pass (128 lanes each).
    for (int pp = 0; pp < TILE_N; pp += 2) {
        int p = pp + (tid >> 7);
        int e = tid & 127;
        if (p < np) {
            long t = wid[p + RADIUS];
            const float* kr = embR + t * (REGION * EMB) + e;
            float m = -INFINITY;
            #pragma unroll
            for (int j = 0; j < REGION; ++j) {
                float ew = wordbuf[p + j][e];
                float kk = kr[(long)j * EMB];
                m = fmaxf(m, ew * kk);
            }
            interL[p][e] = fmaxf(m, 0.f);
        }
    }
    __syncthreads();

    // phase D: 20x16 dot products of length 128
    for (int out = tid; out < NCLS * TILE_N; out += 256) {
        int c = out >> 4;
        int p = out & 15;
        int n = n0 + p;
        if (p < np) {
            float s = 0.f;
            #pragma unroll 8
            for (int e = 0; e < EMB; ++e)
                s += interL[p][e] * wl[c][e];
            interC[((long)b * NCLS + c) * ICP + n] = s;
        }
    }
}

// ---------------------------------------------------------------------------
// Kernel 2: h[m][n] = relu(sum_k interC[m][k] * W_agg1[n][k] + b_agg1[n])
//   M = 1280 (b*20+c), K = 506, N = 1024.
// Block: 256 threads = one n-column-strip of 256, 16 m-rows; interC reads are
// wave-uniform (scalar-load path), W_agg1 rows streamed per thread (L2-hot).
// ---------------------------------------------------------------------------
__global__ __launch_bounds__(256) void k2_gemm(
        const float* __restrict__ interC,
        const float* __restrict__ Wagg1,
        const float* __restrict__ bagg1,
        float*       __restrict__ h) {
    const int n  = blockIdx.x * 256 + threadIdx.x;   // 0..1023
    const int m0 = blockIdx.y * 16;

    float acc[16];
    #pragma unroll
    for (int i = 0; i < 16; ++i) acc[i] = 0.f;

    const float2* w2  = (const float2*)Wagg1 + (long)n * (ENTIRE / 2); // 506 even
    const float*  icb = interC + (long)m0 * ICP;

    // 126 chunks of 4 k-values (k = 0..503)
    for (int kc = 0; kc < 126; ++kc) {
        float2 wa = w2[kc * 2];
        float2 wb = w2[kc * 2 + 1];
        #pragma unroll
        for (int mm = 0; mm < 16; ++mm) {
            float4 ic = *(const float4*)(icb + mm * ICP + kc * 4); // 16B-aligned
            acc[mm] += ic.x * wa.x + ic.y * wa.y + ic.z * wb.x + ic.w * wb.y;
        }
    }
    // tail k = 504, 505
    {
        float wta = Wagg1[(long)n * ENTIRE + 504];
        float wtb = Wagg1[(long)n * ENTIRE + 505];
        #pragma unroll
        for (int mm = 0; mm < 16; ++mm)
            acc[mm] += icb[mm * ICP + 504] * wta + icb[mm * ICP + 505] * wtb;
    }

    float bias = bagg1[n];
    #pragma unroll
    for (int mm = 0; mm < 16; ++mm)
        h[(long)(m0 + mm) * AGG1 + n] = fmaxf(acc[mm] + bias, 0.f);
}

// ---------------------------------------------------------------------------
// Kernel 3: agreg[m] = dot(h[m], W_agg2) + b_agg2   (one wave per m)
// ---------------------------------------------------------------------------
__global__ __launch_bounds__(256) void k3_agreg(
        const float* __restrict__ h,
        const float* __restrict__ Wagg2,
        const float* __restrict__ bagg2,
        float*       __restrict__ out) {
    const int m    = blockIdx.x * 4 + (threadIdx.x >> 6);
    const int lane = threadIdx.x & 63;
    const float* hr = h + (long)m * AGG1;
    float s = 0.f;
    #pragma unroll
    for (int i = 0; i < AGG1 / 64; ++i)
        s += hr[i * 64 + lane] * Wagg2[i * 64 + lane];
    #pragma unroll
    for (int off = 32; off >= 1; off >>= 1)
        s += __shfl_down(s, off, 64);
    if (lane == 0) out[m] = s + bagg2[0];
}

// ---------------------------------------------------------------------------
// Kernel 4: softmax over 20 classes per batch row + argmax (first-max).
// Writes prob to out[1280..2559] and class (as float) to out[2560..2623].
// ---------------------------------------------------------------------------
__global__ void k4_softmax(float* __restrict__ out) {
    int b = threadIdx.x;
    if (b >= BATCH) return;
    float v[NCLS];
    float mx = -INFINITY;
    for (int c = 0; c < NCLS; ++c) {
        v[c] = out[b * NCLS + c];
        mx = fmaxf(mx, v[c]);
    }
    float sum = 0.f;
    for (int c = 0; c < NCLS; ++c) { v[c] = expf(v[c] - mx); sum += v[c]; }
    float inv = 1.f / sum;
    int best = 0; float bv = -INFINITY;
    for (int c = 0; c < NCLS; ++c) {
        float p = v[c] * inv;
        out[BATCH * NCLS + b * NCLS + c] = p;
        if (p > bv) { bv = p; best = c; }
    }
    out[2 * BATCH * NCLS + b] = (float)best;
}

extern "C" void kernel_launch(void* const* d_in, const int* in_sizes, int n_in,
                              void* d_out, int out_size, void* d_ws, size_t ws_size,
                              hipStream_t stream) {
    const int*   ti    = (const int*)  d_in[0];
    const float* embR  = (const float*)d_in[1];
    const float* embW  = (const float*)d_in[2];
    const float* Wint  = (const float*)d_in[3];
    const float* Wagg1 = (const float*)d_in[4];
    const float* bagg1 = (const float*)d_in[5];
    const float* Wagg2 = (const float*)d_in[6];
    const float* bagg2 = (const float*)d_in[7];
    float* out = (float*)d_out;

    float* interC = (float*)d_ws;                         // 1280 * 512 floats
    float* h      = interC + (size_t)BATCH * NCLS * ICP;  // 1280 * 1024 floats

    k1_inter  <<<dim3((ENTIRE + TILE_N - 1) / TILE_N, BATCH), 256, 0, stream>>>(ti, embR, embW, Wint, interC);
    k2_gemm   <<<dim3(AGG1 / 256, BATCH * NCLS / 16),   256, 0, stream>>>(interC, Wagg1, bagg1, h);
    k3_agreg  <<<BATCH * NCLS / 4,                      256, 0, stream>>>(h, Wagg2, bagg2, out);
    k4_softmax<<<1, 64, 0, stream>>>(out);
}

// Round 4
// 250.082 us; speedup vs baseline: 1.1527x; 1.1527x over previous
//
#include <hip/hip_runtime.h>
#include <math.h>

#define BATCH   64
#define MAXLEN  512
#define EMB     128
#define REGION  7
#define RADIUS  3
#define ENTIRE  506          // MAXLEN - 2*RADIUS
#define NCLS    20
#define AGG1    1024         // MAXLEN*2
#define TILE_N  16
#define ICP     512          // interC padded row stride (zero-filled cols 506..511)

// ---------------------------------------------------------------------------
// Kernel 1: per (b, 16-position tile):
//   inter[n][e] = relu(max_j emb_word[w(n+j)][e] * emb_region[w(n+3)][j*128+e])
//   interC[b][c][n] = sum_e inter[n][e] * W_inter[c][e]
// Word-embedding rows staged in LDS (22 rows per tile -> 7x gather reuse).
// Pad columns 506..511 of interC are written as zeros so k2 can run K=512.
// ---------------------------------------------------------------------------
__global__ __launch_bounds__(256) void k1_inter(
        const int*   __restrict__ ti,
        const float* __restrict__ embR,
        const float* __restrict__ embW,
        const float* __restrict__ Wint,
        float*       __restrict__ interC) {
    __shared__ float wordbuf[TILE_N + 6][EMB];
    __shared__ float interL[TILE_N][EMB + 1];
    __shared__ float wl[NCLS][EMB + 2];
    __shared__ int   wid[TILE_N + 6];

    const int b   = blockIdx.y;
    const int n0  = blockIdx.x * TILE_N;
    const int np  = min(TILE_N, ENTIRE - n0);
    const int tid = threadIdx.x;

    if (tid < TILE_N + 6) {
        int r = tid;
        wid[r] = (n0 + r < MAXLEN) ? ti[b * MAXLEN + n0 + r] : 0;
    }
    for (int idx = tid; idx < NCLS * EMB; idx += 256) {
        int c = idx >> 7, e = idx & 127;
        wl[c][e] = Wint[idx];
    }
    __syncthreads();

    for (int idx = tid; idx < (TILE_N + 6) * EMB; idx += 256) {
        int r = idx >> 7, e = idx & 127;
        wordbuf[r][e] = embW[(long)wid[r] * EMB + e];
    }
    __syncthreads();

    #pragma unroll 4
    for (int pp = 0; pp < TILE_N; pp += 2) {
        int p = pp + (tid >> 7);
        int e = tid & 127;
        if (p < np) {
            long t = wid[p + RADIUS];
            const float* kr = embR + t * (REGION * EMB) + e;
            float m = -INFINITY;
            #pragma unroll
            for (int j = 0; j < REGION; ++j) {
                float ew = wordbuf[p + j][e];
                float kk = kr[(long)j * EMB];
                m = fmaxf(m, ew * kk);
            }
            interL[p][e] = fmaxf(m, 0.f);
        }
    }
    __syncthreads();

    for (int oi = tid; oi < NCLS * TILE_N; oi += 256) {
        int c = oi >> 4;
        int p = oi & 15;
        int n = n0 + p;
        if (p < np) {
            float s = 0.f;
            #pragma unroll 8
            for (int e = 0; e < EMB; ++e)
                s += interL[p][e] * wl[c][e];
            interC[((long)b * NCLS + c) * ICP + n] = s;
        } else {
            interC[((long)b * NCLS + c) * ICP + n] = 0.f;  // zero-fill K pad
        }
    }
}

// ---------------------------------------------------------------------------
// Kernel 2: h[m][n] = relu(sum_k interC[m][k] * W_agg1[n][k] + b_agg1[n])
//   M = 1280, K = 506 (padded 512), N = 1024.
// LDS-tiled: BM=64, BN=32, BK=64; 256 thr; micro-tile 4m x 2n strided by 16
// (lane-consecutive rows -> bank-conflict-free ds_read_b128).
// Grid = 32 x 20 = 640 blocks (~2.5 blocks/CU).
// ---------------------------------------------------------------------------
__global__ __launch_bounds__(256) void k2_gemm(
        const float* __restrict__ ic,
        const float* __restrict__ W1,
        const float* __restrict__ b1,
        float*       __restrict__ h) {
    __shared__ float As[64][68];
    __shared__ float Bs[32][68];
    const int tid = threadIdx.x;
    const int n0  = blockIdx.x * 32;
    const int m0  = blockIdx.y * 64;
    const int tm  = tid >> 4;     // 0..15
    const int tn  = tid & 15;     // 0..15

    float acc[4][2] = {{0.f, 0.f}, {0.f, 0.f}, {0.f, 0.f}, {0.f, 0.f}};

    for (int k0 = 0; k0 < 512; k0 += 64) {
        // A tile 64x64, coalesced float4 (ic rows are 512-strided, 16B aligned)
        #pragma unroll
        for (int r = 0; r < 4; ++r) {
            int row = r * 16 + tm;
            *(float4*)&As[row][tn * 4] =
                *(const float4*)&ic[(size_t)(m0 + row) * ICP + k0 + tn * 4];
        }
        // B tile 32x64 from W1 (row stride 506 floats, 8B aligned): float2,
        // zero-guarded for k >= 506
        #pragma unroll
        for (int r = 0; r < 2; ++r) {
            int row = r * 16 + tm;
            #pragma unroll
            for (int j = 0; j < 2; ++j) {
                int col = 2 * tn + 32 * j;
                int gk  = k0 + col;
                float2 v = make_float2(0.f, 0.f);
                if (gk < ENTIRE)
                    v = *(const float2*)&W1[(size_t)(n0 + row) * ENTIRE + gk];
                *(float2*)&Bs[row][col] = v;
            }
        }
        __syncthreads();

        #pragma unroll
        for (int kq = 0; kq < 64; kq += 4) {
            float4 a[4], bb[2];
            #pragma unroll
            for (int i = 0; i < 4; ++i) a[i]  = *(const float4*)&As[tm + 16 * i][kq];
            #pragma unroll
            for (int j = 0; j < 2; ++j) bb[j] = *(const float4*)&Bs[tn + 16 * j][kq];
            #pragma unroll
            for (int i = 0; i < 4; ++i)
                #pragma unroll
                for (int j = 0; j < 2; ++j)
                    acc[i][j] += a[i].x * bb[j].x + a[i].y * bb[j].y
                               + a[i].z * bb[j].z + a[i].w * bb[j].w;
        }
        __syncthreads();
    }

    #pragma unroll
    for (int i = 0; i < 4; ++i) {
        int m = m0 + tm + 16 * i;
        #pragma unroll
        for (int j = 0; j < 2; ++j) {
            int n = n0 + tn + 16 * j;
            h[(size_t)m * AGG1 + n] = fmaxf(acc[i][j] + b1[n], 0.f);
        }
    }
}

// ---------------------------------------------------------------------------
// Kernel 3 (merged agreg + softmax + argmax): one block per batch row.
//   agreg[b][c] = dot(h[b*20+c], W_agg2) + b_agg2
//   prob = softmax(agreg), class = argmax(prob)
// ---------------------------------------------------------------------------
__global__ __launch_bounds__(256) void k3_out(
        const float* __restrict__ h,
        const float* __restrict__ W2,
        const float* __restrict__ b2,
        float*       __restrict__ out) {
    __shared__ float w[AGG1];
    __shared__ float ag[NCLS];
    const int b    = blockIdx.x;
    const int tid  = threadIdx.x;
    const int wv   = tid >> 6;
    const int lane = tid & 63;

    #pragma unroll
    for (int i = 0; i < 4; ++i) w[tid + 256 * i] = W2[tid + 256 * i];
    __syncthreads();

    for (int c = wv; c < NCLS; c += 4) {
        const float* hr = h + ((size_t)b * NCLS + c) * AGG1;
        float s = 0.f;
        #pragma unroll
        for (int i = 0; i < AGG1 / 64; ++i)
            s += hr[i * 64 + lane] * w[i * 64 + lane];
        #pragma unroll
        for (int off = 32; off >= 1; off >>= 1)
            s += __shfl_down(s, off, 64);
        if (lane == 0) ag[c] = s + b2[0];
    }
    __syncthreads();

    if (tid == 0) {
        float mx = -INFINITY;
        for (int c = 0; c < NCLS; ++c) mx = fmaxf(mx, ag[c]);
        float e[NCLS];
        float sum = 0.f;
        for (int c = 0; c < NCLS; ++c) { e[c] = expf(ag[c] - mx); sum += e[c]; }
        float inv = 1.f / sum;
        int best = 0; float bv = -INFINITY;
        for (int c = 0; c < NCLS; ++c) {
            out[b * NCLS + c] = ag[c];
            float p = e[c] * inv;
            out[BATCH * NCLS + b * NCLS + c] = p;
            if (p > bv) { bv = p; best = c; }
        }
        out[2 * BATCH * NCLS + b] = (float)best;
    }
}

extern "C" void kernel_launch(void* const* d_in, const int* in_sizes, int n_in,
                              void* d_out, int out_size, void* d_ws, size_t ws_size,
                              hipStream_t stream) {
    const int*   ti    = (const int*)  d_in[0];
    const float* embR  = (const float*)d_in[1];
    const float* embW  = (const float*)d_in[2];
    const float* Wint  = (const float*)d_in[3];
    const float* Wagg1 = (const float*)d_in[4];
    const float* bagg1 = (const float*)d_in[5];
    const float* Wagg2 = (const float*)d_in[6];
    const float* bagg2 = (const float*)d_in[7];
    float* out = (float*)d_out;

    float* interC = (float*)d_ws;                         // 1280 * 512 floats
    float* h      = interC + (size_t)BATCH * NCLS * ICP;  // 1280 * 1024 floats

    k1_inter<<<dim3((ENTIRE + TILE_N - 1) / TILE_N, BATCH), 256, 0, stream>>>(
        ti, embR, embW, Wint, interC);
    k2_gemm<<<dim3(AGG1 / 32, BATCH * NCLS / 64), 256, 0, stream>>>(
        interC, Wagg1, bagg1, h);
    k3_out<<<BATCH, 256, 0, stream>>>(h, Wagg2, bagg2, out);
}